// Round 6
// baseline (648.939 us; speedup 1.0000x reference)
//
#include <hip/hip_runtime.h>

#define LEAKY_SLOPE 0.01f
#define CBSH 7
#define CBSZ 128          // nodes per coarse bucket

__device__ __forceinline__ unsigned short f2bf(float f) {
    unsigned int u = __builtin_bit_cast(unsigned int, f);
    u = (u + 0x7FFFu + ((u >> 16) & 1u)) >> 16;   // round-to-nearest-even
    return (unsigned short)u;
}
__device__ __forceinline__ float bf2f(unsigned short h) {
    return __builtin_bit_cast(float, ((unsigned int)h) << 16);
}
__device__ __forceinline__ float ulof(unsigned u) {
    return __builtin_bit_cast(float, u << 16);
}
__device__ __forceinline__ float uhif(unsigned u) {
    return __builtin_bit_cast(float, u & 0xFFFF0000u);
}

// ---------------------------------------------------------------------------
// coarse histogram by dst>>7 (LDS-privatized: ~200K global atomics total)
// ---------------------------------------------------------------------------
__global__ __launch_bounds__(256) void chist_kernel(const int* __restrict__ dst,
                                                    int* __restrict__ cbin, int E, int ncb) {
    __shared__ int bins[1024];
    for (int i = threadIdx.x; i < 1024; i += 256) bins[i] = 0;
    __syncthreads();
    int stride = gridDim.x * blockDim.x;
    for (int e = blockIdx.x * blockDim.x + threadIdx.x; e < E; e += stride)
        atomicAdd(&bins[dst[e] >> CBSH], 1);
    __syncthreads();
    for (int i = threadIdx.x; i < ncb; i += 256) {
        int v = bins[i];
        if (v) atomicAdd(&cbin[i], v);
    }
}

// single-block scan of coarse bins -> offsets + cursor init
__global__ __launch_bounds__(256) void cscan_kernel(const int* __restrict__ cbin,
                                                    int* __restrict__ cboff,
                                                    int* __restrict__ ccur, int ncb) {
    __shared__ int s[256];
    __shared__ int carry;
    int t = threadIdx.x;
    if (t == 0) carry = 0;
    __syncthreads();
    for (int base = 0; base < ncb; base += 256) {
        int v = (base + t < ncb) ? cbin[base + t] : 0;
        s[t] = v;
        __syncthreads();
        for (int off = 1; off < 256; off <<= 1) {
            int u = (t >= off) ? s[t - off] : 0;
            __syncthreads();
            s[t] += u;
            __syncthreads();
        }
        int excl = carry + s[t] - v;
        if (base + t < ncb) { cboff[base + t] = excl; ccur[base + t] = excl; }
        __syncthreads();
        if (t == 0) carry += s[255];
        __syncthreads();
    }
    if (t == 0) cboff[ncb] = carry;
}

// level-1 scatter: append packed (src | dlow<<17) to coarse bucket region.
// Bucket frontiers = 782 open lines -> L2-hot, full-line writebacks only.
__global__ void scat1_kernel(const int* __restrict__ src, const int* __restrict__ dst,
                             int* __restrict__ ccur, unsigned* __restrict__ pairs, int E) {
    int e = blockIdx.x * blockDim.x + threadIdx.x;
    if (e < E) {
        int d = dst[e];
        int pos = atomicAdd(&ccur[d >> CBSH], 1);
        pairs[pos] = (unsigned)src[e] | ((unsigned)(d & (CBSZ - 1)) << 17);
    }
}

// per-bucket degree (LDS histogram) -> dis + padded degree (multiple of 16)
__global__ __launch_bounds__(256) void degbuild_kernel(const unsigned* __restrict__ pairs,
                                                       const int* __restrict__ cboff,
                                                       float* __restrict__ dis,
                                                       int* __restrict__ dpad, int n) {
    __shared__ int cnt[CBSZ];
    int t = threadIdx.x;
    int b = blockIdx.x;
    if (t < CBSZ) cnt[t] = 0;
    __syncthreads();
    int e1 = cboff[b + 1];
    for (int e = cboff[b] + t; e < e1; e += 256)
        atomicAdd(&cnt[pairs[e] >> 17], 1);
    __syncthreads();
    if (t < CBSZ) {
        int node = b * CBSZ + t;
        if (node < n) {
            int d = cnt[t];
            dis[node] = rsqrtf((float)d + 1.0f);
            dpad[node] = (d + 15) & ~15;
        }
    }
}

// ---------------------------------------------------------------------------
// scan chain over padded degrees -> rp (padded CSR offsets)
// ---------------------------------------------------------------------------
__global__ void scan_block_sums(const int* __restrict__ deg, int* __restrict__ bsum, int n) {
    __shared__ int sdata[256];
    int i = blockIdx.x * 256 + threadIdx.x;
    int t = threadIdx.x;
    sdata[t] = (i < n) ? deg[i] : 0;
    __syncthreads();
    for (int s = 128; s > 0; s >>= 1) {
        if (t < s) sdata[t] += sdata[t + s];
        __syncthreads();
    }
    if (t == 0) bsum[blockIdx.x] = sdata[0];
}

__global__ void scan_partials(int* __restrict__ bsum, int nb, int* __restrict__ rp_end) {
    __shared__ int s[512];
    int t = threadIdx.x;
    int orig = (t < nb) ? bsum[t] : 0;
    s[t] = orig;
    __syncthreads();
    for (int off = 1; off < 512; off <<= 1) {
        int v = (t >= off) ? s[t - off] : 0;
        __syncthreads();
        s[t] += v;
        __syncthreads();
    }
    if (t < nb) bsum[t] = s[t] - orig;   // exclusive
    if (t == 0) rp_end[0] = s[511];      // total padded edges
}

__global__ void scan_final(const int* __restrict__ deg, const int* __restrict__ bsum,
                           int* __restrict__ rp, int n) {
    __shared__ int s[256];
    int i = blockIdx.x * 256 + threadIdx.x;
    int t = threadIdx.x;
    int orig = (i < n) ? deg[i] : 0;
    s[t] = orig;
    __syncthreads();
    for (int off = 1; off < 256; off <<= 1) {
        int v = (t >= off) ? s[t - off] : 0;
        __syncthreads();
        s[t] += v;
        __syncthreads();
    }
    if (i < n) rp[i] = s[t] - orig + bsum[blockIdx.x];
}

// prefill padded edge array with dummy index (= n, a zero row)
__global__ void prefill_kernel(int* __restrict__ ssrc, int val, int total) {
    int i = blockIdx.x * blockDim.x + threadIdx.x;
    if (i < total) ssrc[i] = val;
}

// level-2 scatter: within each 128-node bucket, place edges at exact padded
// CSR positions via LDS cursors. Writes land in a ~12KB L2-hot window.
__global__ __launch_bounds__(256) void scat2_kernel(const unsigned* __restrict__ pairs,
                                                    const int* __restrict__ cboff,
                                                    const int* __restrict__ rp,
                                                    int* __restrict__ ssrc, int n) {
    __shared__ int lrp[CBSZ];
    __shared__ int lcnt[CBSZ];
    int t = threadIdx.x;
    int b = blockIdx.x;
    if (t < CBSZ) {
        int node = b * CBSZ + t;
        lrp[t] = (node < n) ? rp[node] : 0;
        lcnt[t] = 0;
    }
    __syncthreads();
    int e1 = cboff[b + 1];
    for (int e = cboff[b] + t; e < e1; e += 256) {
        unsigned p = pairs[e];
        int dl = p >> 17;
        int off = atomicAdd(&lcnt[dl], 1);
        ssrc[lrp[dl] + off] = (int)(p & 0x1FFFFu);
    }
}

// ---------------------------------------------------------------------------
// gemm1: Hs1 = (X[N,128] @ W1[128,64]) * dis -> bf16
// ---------------------------------------------------------------------------
__global__ __launch_bounds__(256) void gemm1_kernel(const float* __restrict__ X,
                                                    const float* __restrict__ W,
                                                    const float* __restrict__ dis,
                                                    unsigned short* __restrict__ Hh, int N) {
    __shared__ float Xs[16 * 128];
    int tid = threadIdx.x;
    int row0 = blockIdx.x * 16;
    for (int i = tid * 4; i < 16 * 128; i += 256 * 4)
        *(float4*)&Xs[i] = *(const float4*)&X[(size_t)row0 * 128 + i];
    __syncthreads();

    int c = tid & 63;
    int g = tid >> 6;
    float acc[4] = {0.f, 0.f, 0.f, 0.f};
    for (int kk = 0; kk < 128; kk += 16) {
        float w[16];
#pragma unroll
        for (int k = 0; k < 16; ++k) w[k] = W[(kk + k) * 64 + c];
#pragma unroll
        for (int r = 0; r < 4; ++r) {
            int row = g + r * 4;
#pragma unroll
            for (int k4 = 0; k4 < 16; k4 += 4) {
                float4 x4 = *(float4*)&Xs[row * 128 + kk + k4];
                acc[r] += x4.x * w[k4] + x4.y * w[k4 + 1] + x4.z * w[k4 + 2] + x4.w * w[k4 + 3];
            }
        }
    }
#pragma unroll
    for (int r = 0; r < 4; ++r) {
        int row = row0 + g + r * 4;
        Hh[(size_t)row * 64 + c] = f2bf(acc[r] * dis[row]);
    }
}

// ---------------------------------------------------------------------------
// Wide gather: 4 lane-groups x 16 lanes; each lane loads ushort4 (4 channels,
// 8B) -> one load instr fetches 4 edge rows; 16 edges in flight per body.
// Edge lists padded to x16 with dummy row n (zeros) -> no tail code.
// Ends with cross-group reduce + redistribute to lane==channel layout.
// ---------------------------------------------------------------------------
#define GATHER_WIDE(Hh, wid, lane, accv)                                       \
    float accv;                                                                \
    {                                                                          \
        int gg = (lane) >> 4, cc = (lane) & 15;                                \
        float ac0 = 0.f, ac1 = 0.f, ac2 = 0.f, ac3 = 0.f;                      \
        int e0 = rp[wid], e1 = rp[(wid) + 1];                                  \
        const int* sp = ssrc + e0;                                             \
        int cnt = e1 - e0;                                                     \
        for (int i = 0; i < cnt; i += 16) {                                    \
            int s0 = sp[i + gg];                                               \
            int s1 = sp[i + gg + 4];                                           \
            int s2 = sp[i + gg + 8];                                           \
            int s3 = sp[i + gg + 12];                                          \
            uint2 q0 = *(const uint2*)&Hh[(size_t)s0 * 64 + cc * 4];           \
            uint2 q1 = *(const uint2*)&Hh[(size_t)s1 * 64 + cc * 4];           \
            uint2 q2 = *(const uint2*)&Hh[(size_t)s2 * 64 + cc * 4];           \
            uint2 q3 = *(const uint2*)&Hh[(size_t)s3 * 64 + cc * 4];           \
            ac0 += (ulof(q0.x) + ulof(q1.x)) + (ulof(q2.x) + ulof(q3.x));      \
            ac1 += (uhif(q0.x) + uhif(q1.x)) + (uhif(q2.x) + uhif(q3.x));      \
            ac2 += (ulof(q0.y) + ulof(q1.y)) + (ulof(q2.y) + ulof(q3.y));      \
            ac3 += (uhif(q0.y) + uhif(q1.y)) + (uhif(q2.y) + uhif(q3.y));      \
        }                                                                      \
        ac0 += __shfl_xor(ac0, 16); ac0 += __shfl_xor(ac0, 32);                \
        ac1 += __shfl_xor(ac1, 16); ac1 += __shfl_xor(ac1, 32);                \
        ac2 += __shfl_xor(ac2, 16); ac2 += __shfl_xor(ac2, 32);                \
        ac3 += __shfl_xor(ac3, 16); ac3 += __shfl_xor(ac3, 32);                \
        int srcl = (lane) >> 2;                                                \
        float v0 = __shfl(ac0, srcl);                                          \
        float v1 = __shfl(ac1, srcl);                                          \
        float v2 = __shfl(ac2, srcl);                                          \
        float v3 = __shfl(ac3, srcl);                                          \
        int jj = (lane) & 3;                                                   \
        accv = jj == 0 ? v0 : (jj == 1 ? v1 : (jj == 2 ? v2 : v3));            \
        accv += bf2f(Hh[(size_t)(wid) * 64 + (lane)]);                         \
    }

// ---------------------------------------------------------------------------
// aggA: h1 = leaky(dis*agg(Hs1) + b1); Hs2 = (h1 @ W2)*dis -> bf16
// ---------------------------------------------------------------------------
__global__ __launch_bounds__(256) void aggA_kernel(
    const unsigned short* __restrict__ Hh, const int* __restrict__ rp,
    const int* __restrict__ ssrc, const float* __restrict__ dis,
    const float* __restrict__ b1, const float* __restrict__ W2,
    unsigned short* __restrict__ Oh, int n) {
    int lane = threadIdx.x & 63;
    float wc[64];
#pragma unroll
    for (int k = 0; k < 64; ++k) wc[k] = W2[k * 64 + lane];
    float bias = b1[lane];

    int wid = (int)((blockIdx.x * blockDim.x + threadIdx.x) >> 6);
    int nwaves = (int)((gridDim.x * blockDim.x) >> 6);
    for (; wid < n; wid += nwaves) {
        GATHER_WIDE(Hh, wid, lane, accv)
        float d = dis[wid];
        float h = fmaf(accv, d, bias);
        h = h > 0.f ? h : LEAKY_SLOPE * h;
        int hb = __builtin_bit_cast(int, h);
        float o = 0.f;
#pragma unroll
        for (int k = 0; k < 64; ++k) {
            float hk = __builtin_bit_cast(float, __builtin_amdgcn_readlane(hb, k));
            o = fmaf(hk, wc[k], o);
        }
        Oh[(size_t)wid * 64 + lane] = f2bf(o * d);
    }
}

// ---------------------------------------------------------------------------
// aggB: h2 = leaky(dis*agg(Hs2) + b2); h2s = h2*dis -> bf16
// ---------------------------------------------------------------------------
__global__ __launch_bounds__(256) void aggB_kernel(
    const unsigned short* __restrict__ Hh, const int* __restrict__ rp,
    const int* __restrict__ ssrc, const float* __restrict__ dis,
    const float* __restrict__ b2, unsigned short* __restrict__ Oh, int n) {
    int lane = threadIdx.x & 63;
    float bias = b2[lane];
    int wid = (int)((blockIdx.x * blockDim.x + threadIdx.x) >> 6);
    int nwaves = (int)((gridDim.x * blockDim.x) >> 6);
    for (; wid < n; wid += nwaves) {
        GATHER_WIDE(Hh, wid, lane, accv)
        float d = dis[wid];
        float h = fmaf(accv, d, bias);
        h = h > 0.f ? h : LEAKY_SLOPE * h;
        Oh[(size_t)wid * 64 + lane] = f2bf(h * d);
    }
}

// ---------------------------------------------------------------------------
// aggC: g = dis*agg(h2s); mu = g@Wmu + bmu; ls = g@Wls + bls -> d_out
// ---------------------------------------------------------------------------
__global__ __launch_bounds__(256) void aggC_kernel(
    const unsigned short* __restrict__ Hh, const int* __restrict__ rp,
    const int* __restrict__ ssrc, const float* __restrict__ dis,
    const float* __restrict__ Wmu, const float* __restrict__ bmu,
    const float* __restrict__ Wls, const float* __restrict__ bls,
    float* __restrict__ mu, float* __restrict__ ls, int n) {
    int lane = threadIdx.x & 63;
    int half = lane >> 5;
    int c = lane & 31;
    const float* Wp = half ? Wls : Wmu;
    float wc[64];
#pragma unroll
    for (int k = 0; k < 64; ++k) wc[k] = Wp[k * 32 + c];
    float bias = half ? bls[c] : bmu[c];
    float* outp = half ? ls : mu;

    int wid = (int)((blockIdx.x * blockDim.x + threadIdx.x) >> 6);
    int nwaves = (int)((gridDim.x * blockDim.x) >> 6);
    for (; wid < n; wid += nwaves) {
        GATHER_WIDE(Hh, wid, lane, accv)
        float gval = accv * dis[wid];
        int gb = __builtin_bit_cast(int, gval);
        float o = bias;
#pragma unroll
        for (int k = 0; k < 64; ++k) {
            float gk = __builtin_bit_cast(float, __builtin_amdgcn_readlane(gb, k));
            o = fmaf(gk, wc[k], o);
        }
        outp[(size_t)wid * 32 + c] = o;
    }
}

// ---------------------------------------------------------------------------
extern "C" void kernel_launch(void* const* d_in, const int* in_sizes, int n_in,
                              void* d_out, int out_size, void* d_ws, size_t ws_size,
                              hipStream_t stream) {
    const float* x   = (const float*)d_in[0];
    const int*   ei  = (const int*)d_in[1];
    const float* W1  = (const float*)d_in[2];
    const float* b1  = (const float*)d_in[3];
    const float* W2  = (const float*)d_in[4];
    const float* b2  = (const float*)d_in[5];
    const float* Wmu = (const float*)d_in[6];
    const float* bmu = (const float*)d_in[7];
    const float* Wls = (const float*)d_in[8];
    const float* bls = (const float*)d_in[9];

    const int N = in_sizes[0] / 128;   // 100000
    const int E = in_sizes[1] / 2;     // 1600000
    const int NCB = (N + CBSZ - 1) / CBSZ;   // 782 coarse buckets
    const int PADMAX = E + 15 * ((N + 15) / 16) * 16 + 64;  // padded edges upper bound
    const int* src  = ei;
    const int* dstp = ei + E;

    auto align64 = [](size_t v) { return (v + 63) & ~(size_t)63; };
    char* ws = (char*)d_ws;
    int*   dpad  = (int*)ws;   ws += align64((size_t)N * 4);
    float* dis   = (float*)ws; ws += align64((size_t)N * 4);
    int*   cbin  = (int*)ws;   ws += align64(1024 * 4);
    int*   cboff = (int*)ws;   ws += align64(1025 * 4);
    int*   ccur  = (int*)ws;   ws += align64(1024 * 4);
    int*   bsum  = (int*)ws;   ws += 4096;
    int*   rp    = (int*)ws;   ws += align64((size_t)(N + 1) * 4);
    unsigned* pairs = (unsigned*)ws; ws += align64((size_t)E * 4);
    int*   ssrc  = (int*)ws;   ws += align64((size_t)PADMAX * 4);
    unsigned short* bufH0 = (unsigned short*)ws; ws += align64(((size_t)N + 1) * 64 * 2);
    unsigned short* bufH1 = (unsigned short*)ws; ws += align64(((size_t)N + 1) * 64 * 2);

    float* mu = (float*)d_out;
    float* ls = mu + (size_t)N * 32;

    const int eblocks = (E + 255) / 256;   // 6250
    const int nblocks = (N + 255) / 256;   // 391

    // ---- 2-level counting sort into padded CSR ----
    hipMemsetAsync(cbin, 0, 1024 * sizeof(int), stream);
    prefill_kernel<<<(PADMAX + 255) / 256, 256, 0, stream>>>(ssrc, N, PADMAX);
    chist_kernel<<<256, 256, 0, stream>>>(dstp, cbin, E, NCB);
    cscan_kernel<<<1, 256, 0, stream>>>(cbin, cboff, ccur, NCB);
    scat1_kernel<<<eblocks, 256, 0, stream>>>(src, dstp, ccur, pairs, E);
    degbuild_kernel<<<NCB, 256, 0, stream>>>(pairs, cboff, dis, dpad, N);
    scan_block_sums<<<nblocks, 256, 0, stream>>>(dpad, bsum, N);
    scan_partials<<<1, 512, 0, stream>>>(bsum, nblocks, rp + N);
    scan_final<<<nblocks, 256, 0, stream>>>(dpad, bsum, rp, N);
    scat2_kernel<<<NCB, 256, 0, stream>>>(pairs, cboff, rp, ssrc, N);

    // ---- Hs1 = (x@W1)*dis (bf16); zero dummy row N in both buffers ----
    gemm1_kernel<<<N / 16, 256, 0, stream>>>(x, W1, dis, bufH0, N);
    hipMemsetAsync(bufH0 + (size_t)N * 64, 0, 128, stream);
    hipMemsetAsync(bufH1 + (size_t)N * 64, 0, 128, stream);

    const int aggblocks = 2048;  // 8192 waves, grid-stride

    aggA_kernel<<<aggblocks, 256, 0, stream>>>(bufH0, rp, ssrc, dis, b1, W2, bufH1, N);
    aggB_kernel<<<aggblocks, 256, 0, stream>>>(bufH1, rp, ssrc, dis, b2, bufH0, N);
    aggC_kernel<<<aggblocks, 256, 0, stream>>>(bufH0, rp, ssrc, dis, Wmu, bmu,
                                               Wls, bls, mu, ls, N);
}

// Round 7
// 307.368 us; speedup vs baseline: 2.1113x; 2.1113x over previous
//
#include <hip/hip_runtime.h>

#define LEAKY_SLOPE 0.01f
#define CBSH 7
#define CBSZ 128          // nodes per coarse bucket
#define CHUNK 4096        // edges per scat1 block

__device__ __forceinline__ unsigned short f2bf(float f) {
    unsigned int u = __builtin_bit_cast(unsigned int, f);
    u = (u + 0x7FFFu + ((u >> 16) & 1u)) >> 16;   // round-to-nearest-even
    return (unsigned short)u;
}
__device__ __forceinline__ float bf2f(unsigned short h) {
    return __builtin_bit_cast(float, ((unsigned int)h) << 16);
}
__device__ __forceinline__ float ulof(unsigned u) {
    return __builtin_bit_cast(float, u << 16);
}
__device__ __forceinline__ float uhif(unsigned u) {
    return __builtin_bit_cast(float, u & 0xFFFF0000u);
}

// ---------------------------------------------------------------------------
// coarse histogram by dst>>7 (LDS-privatized)
// ---------------------------------------------------------------------------
__global__ __launch_bounds__(256) void chist_kernel(const int* __restrict__ dst,
                                                    int* __restrict__ cbin, int E, int ncb) {
    __shared__ int bins[1024];
    for (int i = threadIdx.x; i < 1024; i += 256) bins[i] = 0;
    __syncthreads();
    int stride = gridDim.x * blockDim.x;
    for (int e = blockIdx.x * blockDim.x + threadIdx.x; e < E; e += stride)
        atomicAdd(&bins[dst[e] >> CBSH], 1);
    __syncthreads();
    for (int i = threadIdx.x; i < ncb; i += 256) {
        int v = bins[i];
        if (v) atomicAdd(&cbin[i], v);
    }
}

// single-block scan of coarse bins -> offsets + 64B-strided cursor init
__global__ __launch_bounds__(256) void cscan_kernel(const int* __restrict__ cbin,
                                                    int* __restrict__ cboff,
                                                    int* __restrict__ ccur16, int ncb) {
    __shared__ int s[256];
    __shared__ int carry;
    int t = threadIdx.x;
    if (t == 0) carry = 0;
    __syncthreads();
    for (int base = 0; base < ncb; base += 256) {
        int v = (base + t < ncb) ? cbin[base + t] : 0;
        s[t] = v;
        __syncthreads();
        for (int off = 1; off < 256; off <<= 1) {
            int u = (t >= off) ? s[t - off] : 0;
            __syncthreads();
            s[t] += u;
            __syncthreads();
        }
        int excl = carry + s[t] - v;
        if (base + t < ncb) { cboff[base + t] = excl; ccur16[(size_t)(base + t) * 16] = excl; }
        __syncthreads();
        if (t == 0) carry += s[255];
        __syncthreads();
    }
    if (t == 0) cboff[ncb] = carry;
}

// ---------------------------------------------------------------------------
// blocked level-1 scatter: per-block LDS histogram -> one global atomic per
// (block,bucket) chunk reservation (64B-strided cursors, no false sharing) ->
// LDS-cursor scatter. ~306K global atomics instead of 1.6M contended ones.
// ---------------------------------------------------------------------------
__global__ __launch_bounds__(256) void scat1_kernel(const int* __restrict__ src,
                                                    const int* __restrict__ dst,
                                                    int* __restrict__ ccur16,
                                                    unsigned* __restrict__ pairs, int E) {
    __shared__ int bins[1024];
    __shared__ int base[1024];
    int t = threadIdx.x;
    for (int i = t; i < 1024; i += 256) bins[i] = 0;
    __syncthreads();
    int e0 = blockIdx.x * CHUNK;
    int m = min(CHUNK, E - e0);
    for (int i = t; i < m; i += 256)
        atomicAdd(&bins[dst[e0 + i] >> CBSH], 1);
    __syncthreads();
    for (int i = t; i < 1024; i += 256) {
        int c = bins[i];
        base[i] = c ? atomicAdd(&ccur16[(size_t)i * 16], c) : 0;
        bins[i] = 0;   // reuse as local cursor
    }
    __syncthreads();
    for (int i = t; i < m; i += 256) {
        int d = dst[e0 + i];
        int b = d >> CBSH;
        int off = atomicAdd(&bins[b], 1);
        pairs[base[b] + off] = (unsigned)src[e0 + i] | ((unsigned)(d & (CBSZ - 1)) << 17);
    }
}

// per-bucket degree (LDS histogram) -> dis + padded degree (multiple of 16)
__global__ __launch_bounds__(256) void degbuild_kernel(const unsigned* __restrict__ pairs,
                                                       const int* __restrict__ cboff,
                                                       float* __restrict__ dis,
                                                       int* __restrict__ dpad, int n) {
    __shared__ int cnt[CBSZ];
    int t = threadIdx.x;
    int b = blockIdx.x;
    if (t < CBSZ) cnt[t] = 0;
    __syncthreads();
    int e1 = cboff[b + 1];
    for (int e = cboff[b] + t; e < e1; e += 256)
        atomicAdd(&cnt[pairs[e] >> 17], 1);
    __syncthreads();
    if (t < CBSZ) {
        int node = b * CBSZ + t;
        if (node < n) {
            int d = cnt[t];
            dis[node] = rsqrtf((float)d + 1.0f);
            dpad[node] = (d + 15) & ~15;
        }
    }
}

// ---------------------------------------------------------------------------
// scan chain over padded degrees -> rp (padded CSR offsets)
// ---------------------------------------------------------------------------
__global__ void scan_block_sums(const int* __restrict__ deg, int* __restrict__ bsum, int n) {
    __shared__ int sdata[256];
    int i = blockIdx.x * 256 + threadIdx.x;
    int t = threadIdx.x;
    sdata[t] = (i < n) ? deg[i] : 0;
    __syncthreads();
    for (int s = 128; s > 0; s >>= 1) {
        if (t < s) sdata[t] += sdata[t + s];
        __syncthreads();
    }
    if (t == 0) bsum[blockIdx.x] = sdata[0];
}

__global__ void scan_partials(int* __restrict__ bsum, int nb, int* __restrict__ rp_end) {
    __shared__ int s[512];
    int t = threadIdx.x;
    int orig = (t < nb) ? bsum[t] : 0;
    s[t] = orig;
    __syncthreads();
    for (int off = 1; off < 512; off <<= 1) {
        int v = (t >= off) ? s[t - off] : 0;
        __syncthreads();
        s[t] += v;
        __syncthreads();
    }
    if (t < nb) bsum[t] = s[t] - orig;   // exclusive
    if (t == 0) rp_end[0] = s[511];      // total padded edges
}

__global__ void scan_final(const int* __restrict__ deg, const int* __restrict__ bsum,
                           int* __restrict__ rp, int n) {
    __shared__ int s[256];
    int i = blockIdx.x * 256 + threadIdx.x;
    int t = threadIdx.x;
    int orig = (i < n) ? deg[i] : 0;
    s[t] = orig;
    __syncthreads();
    for (int off = 1; off < 256; off <<= 1) {
        int v = (t >= off) ? s[t - off] : 0;
        __syncthreads();
        s[t] += v;
        __syncthreads();
    }
    if (i < n) rp[i] = s[t] - orig + bsum[blockIdx.x];
}

// prefill padded edge array with dummy index (= n, a zero row)
__global__ void prefill_kernel(int* __restrict__ ssrc, int val, int total) {
    int i = blockIdx.x * blockDim.x + threadIdx.x;
    if (i < total) ssrc[i] = val;
}

// level-2 scatter: within each 128-node bucket, place edges at exact padded
// CSR positions via LDS cursors. Writes land in a ~12KB L2-hot window.
__global__ __launch_bounds__(256) void scat2_kernel(const unsigned* __restrict__ pairs,
                                                    const int* __restrict__ cboff,
                                                    const int* __restrict__ rp,
                                                    int* __restrict__ ssrc, int n) {
    __shared__ int lrp[CBSZ];
    __shared__ int lcnt[CBSZ];
    int t = threadIdx.x;
    int b = blockIdx.x;
    if (t < CBSZ) {
        int node = b * CBSZ + t;
        lrp[t] = (node < n) ? rp[node] : 0;
        lcnt[t] = 0;
    }
    __syncthreads();
    int e1 = cboff[b + 1];
    for (int e = cboff[b] + t; e < e1; e += 256) {
        unsigned p = pairs[e];
        int dl = p >> 17;
        int off = atomicAdd(&lcnt[dl], 1);
        ssrc[lrp[dl] + off] = (int)(p & 0x1FFFFu);
    }
}

// ---------------------------------------------------------------------------
// gemm1: Hs1 = (X[N,128] @ W1[128,64]) * dis -> bf16
// ---------------------------------------------------------------------------
__global__ __launch_bounds__(256) void gemm1_kernel(const float* __restrict__ X,
                                                    const float* __restrict__ W,
                                                    const float* __restrict__ dis,
                                                    unsigned short* __restrict__ Hh, int N) {
    __shared__ float Xs[16 * 128];
    int tid = threadIdx.x;
    int row0 = blockIdx.x * 16;
    for (int i = tid * 4; i < 16 * 128; i += 256 * 4)
        *(float4*)&Xs[i] = *(const float4*)&X[(size_t)row0 * 128 + i];
    __syncthreads();

    int c = tid & 63;
    int g = tid >> 6;
    float acc[4] = {0.f, 0.f, 0.f, 0.f};
    for (int kk = 0; kk < 128; kk += 16) {
        float w[16];
#pragma unroll
        for (int k = 0; k < 16; ++k) w[k] = W[(kk + k) * 64 + c];
#pragma unroll
        for (int r = 0; r < 4; ++r) {
            int row = g + r * 4;
#pragma unroll
            for (int k4 = 0; k4 < 16; k4 += 4) {
                float4 x4 = *(float4*)&Xs[row * 128 + kk + k4];
                acc[r] += x4.x * w[k4] + x4.y * w[k4 + 1] + x4.z * w[k4 + 2] + x4.w * w[k4 + 3];
            }
        }
    }
#pragma unroll
    for (int r = 0; r < 4; ++r) {
        int row = row0 + g + r * 4;
        Hh[(size_t)row * 64 + c] = f2bf(acc[r] * dis[row]);
    }
}

// ---------------------------------------------------------------------------
// Wide gather: 4 lane-groups x 16 lanes; each lane loads ushort4 (4 channels,
// 8B) -> one load instr fetches 4 edge rows; 16 edges in flight per body.
// Edge lists padded to x16 with dummy row n (zeros) -> no tail code.
// ---------------------------------------------------------------------------
#define GATHER_WIDE(Hh, wid, lane, accv)                                       \
    float accv;                                                                \
    {                                                                          \
        int gg = (lane) >> 4, cc = (lane) & 15;                                \
        float ac0 = 0.f, ac1 = 0.f, ac2 = 0.f, ac3 = 0.f;                      \
        int e0 = rp[wid], e1 = rp[(wid) + 1];                                  \
        const int* sp = ssrc + e0;                                             \
        int cnt = e1 - e0;                                                     \
        for (int i = 0; i < cnt; i += 16) {                                    \
            int s0 = sp[i + gg];                                               \
            int s1 = sp[i + gg + 4];                                           \
            int s2 = sp[i + gg + 8];                                           \
            int s3 = sp[i + gg + 12];                                          \
            uint2 q0 = *(const uint2*)&Hh[(size_t)s0 * 64 + cc * 4];           \
            uint2 q1 = *(const uint2*)&Hh[(size_t)s1 * 64 + cc * 4];           \
            uint2 q2 = *(const uint2*)&Hh[(size_t)s2 * 64 + cc * 4];           \
            uint2 q3 = *(const uint2*)&Hh[(size_t)s3 * 64 + cc * 4];           \
            ac0 += (ulof(q0.x) + ulof(q1.x)) + (ulof(q2.x) + ulof(q3.x));      \
            ac1 += (uhif(q0.x) + uhif(q1.x)) + (uhif(q2.x) + uhif(q3.x));      \
            ac2 += (ulof(q0.y) + ulof(q1.y)) + (ulof(q2.y) + ulof(q3.y));      \
            ac3 += (uhif(q0.y) + uhif(q1.y)) + (uhif(q2.y) + uhif(q3.y));      \
        }                                                                      \
        ac0 += __shfl_xor(ac0, 16); ac0 += __shfl_xor(ac0, 32);                \
        ac1 += __shfl_xor(ac1, 16); ac1 += __shfl_xor(ac1, 32);                \
        ac2 += __shfl_xor(ac2, 16); ac2 += __shfl_xor(ac2, 32);                \
        ac3 += __shfl_xor(ac3, 16); ac3 += __shfl_xor(ac3, 32);                \
        int srcl = (lane) >> 2;                                                \
        float v0 = __shfl(ac0, srcl);                                          \
        float v1 = __shfl(ac1, srcl);                                          \
        float v2 = __shfl(ac2, srcl);                                          \
        float v3 = __shfl(ac3, srcl);                                          \
        int jj = (lane) & 3;                                                   \
        accv = jj == 0 ? v0 : (jj == 1 ? v1 : (jj == 2 ? v2 : v3));            \
        accv += bf2f(Hh[(size_t)(wid) * 64 + (lane)]);                         \
    }

// ---------------------------------------------------------------------------
// aggA: h1 = leaky(dis*agg(Hs1) + b1); Hs2 = (h1 @ W2)*dis -> bf16
// ---------------------------------------------------------------------------
__global__ __launch_bounds__(256) void aggA_kernel(
    const unsigned short* __restrict__ Hh, const int* __restrict__ rp,
    const int* __restrict__ ssrc, const float* __restrict__ dis,
    const float* __restrict__ b1, const float* __restrict__ W2,
    unsigned short* __restrict__ Oh, int n) {
    int lane = threadIdx.x & 63;
    float wc[64];
#pragma unroll
    for (int k = 0; k < 64; ++k) wc[k] = W2[k * 64 + lane];
    float bias = b1[lane];

    int wid = (int)((blockIdx.x * blockDim.x + threadIdx.x) >> 6);
    int nwaves = (int)((gridDim.x * blockDim.x) >> 6);
    for (; wid < n; wid += nwaves) {
        GATHER_WIDE(Hh, wid, lane, accv)
        float d = dis[wid];
        float h = fmaf(accv, d, bias);
        h = h > 0.f ? h : LEAKY_SLOPE * h;
        int hb = __builtin_bit_cast(int, h);
        float o = 0.f;
#pragma unroll
        for (int k = 0; k < 64; ++k) {
            float hk = __builtin_bit_cast(float, __builtin_amdgcn_readlane(hb, k));
            o = fmaf(hk, wc[k], o);
        }
        Oh[(size_t)wid * 64 + lane] = f2bf(o * d);
    }
}

// ---------------------------------------------------------------------------
// aggB: h2 = leaky(dis*agg(Hs2) + b2); h2s = h2*dis -> bf16
// ---------------------------------------------------------------------------
__global__ __launch_bounds__(256) void aggB_kernel(
    const unsigned short* __restrict__ Hh, const int* __restrict__ rp,
    const int* __restrict__ ssrc, const float* __restrict__ dis,
    const float* __restrict__ b2, unsigned short* __restrict__ Oh, int n) {
    int lane = threadIdx.x & 63;
    float bias = b2[lane];
    int wid = (int)((blockIdx.x * blockDim.x + threadIdx.x) >> 6);
    int nwaves = (int)((gridDim.x * blockDim.x) >> 6);
    for (; wid < n; wid += nwaves) {
        GATHER_WIDE(Hh, wid, lane, accv)
        float d = dis[wid];
        float h = fmaf(accv, d, bias);
        h = h > 0.f ? h : LEAKY_SLOPE * h;
        Oh[(size_t)wid * 64 + lane] = f2bf(h * d);
    }
}

// ---------------------------------------------------------------------------
// aggC: g = dis*agg(h2s); mu = g@Wmu + bmu; ls = g@Wls + bls -> d_out
// ---------------------------------------------------------------------------
__global__ __launch_bounds__(256) void aggC_kernel(
    const unsigned short* __restrict__ Hh, const int* __restrict__ rp,
    const int* __restrict__ ssrc, const float* __restrict__ dis,
    const float* __restrict__ Wmu, const float* __restrict__ bmu,
    const float* __restrict__ Wls, const float* __restrict__ bls,
    float* __restrict__ mu, float* __restrict__ ls, int n) {
    int lane = threadIdx.x & 63;
    int half = lane >> 5;
    int c = lane & 31;
    const float* Wp = half ? Wls : Wmu;
    float wc[64];
#pragma unroll
    for (int k = 0; k < 64; ++k) wc[k] = Wp[k * 32 + c];
    float bias = half ? bls[c] : bmu[c];
    float* outp = half ? ls : mu;

    int wid = (int)((blockIdx.x * blockDim.x + threadIdx.x) >> 6);
    int nwaves = (int)((gridDim.x * blockDim.x) >> 6);
    for (; wid < n; wid += nwaves) {
        GATHER_WIDE(Hh, wid, lane, accv)
        float gval = accv * dis[wid];
        int gb = __builtin_bit_cast(int, gval);
        float o = bias;
#pragma unroll
        for (int k = 0; k < 64; ++k) {
            float gk = __builtin_bit_cast(float, __builtin_amdgcn_readlane(gb, k));
            o = fmaf(gk, wc[k], o);
        }
        outp[(size_t)wid * 32 + c] = o;
    }
}

// ---------------------------------------------------------------------------
extern "C" void kernel_launch(void* const* d_in, const int* in_sizes, int n_in,
                              void* d_out, int out_size, void* d_ws, size_t ws_size,
                              hipStream_t stream) {
    const float* x   = (const float*)d_in[0];
    const int*   ei  = (const int*)d_in[1];
    const float* W1  = (const float*)d_in[2];
    const float* b1  = (const float*)d_in[3];
    const float* W2  = (const float*)d_in[4];
    const float* b2  = (const float*)d_in[5];
    const float* Wmu = (const float*)d_in[6];
    const float* bmu = (const float*)d_in[7];
    const float* Wls = (const float*)d_in[8];
    const float* bls = (const float*)d_in[9];

    const int N = in_sizes[0] / 128;   // 100000
    const int E = in_sizes[1] / 2;     // 1600000
    const int NCB = (N + CBSZ - 1) / CBSZ;   // 782 coarse buckets
    const int PADMAX = E + 15 * ((N + 15) / 16) * 16 + 64;  // padded edges upper bound
    const int* src  = ei;
    const int* dstp = ei + E;

    auto align64 = [](size_t v) { return (v + 63) & ~(size_t)63; };
    char* ws = (char*)d_ws;
    int*   dpad   = (int*)ws;   ws += align64((size_t)N * 4);
    float* dis    = (float*)ws; ws += align64((size_t)N * 4);
    int*   cbin   = (int*)ws;   ws += align64(1024 * 4);
    int*   cboff  = (int*)ws;   ws += align64(1025 * 4);
    int*   ccur16 = (int*)ws;   ws += align64((size_t)1024 * 16 * 4);
    int*   bsum   = (int*)ws;   ws += 4096;
    int*   rp     = (int*)ws;   ws += align64((size_t)(N + 1) * 4);
    unsigned* pairs = (unsigned*)ws; ws += align64((size_t)E * 4);
    int*   ssrc   = (int*)ws;   ws += align64((size_t)PADMAX * 4);
    unsigned short* bufH0 = (unsigned short*)ws; ws += align64(((size_t)N + 1) * 64 * 2);
    unsigned short* bufH1 = (unsigned short*)ws; ws += align64(((size_t)N + 1) * 64 * 2);

    float* mu = (float*)d_out;
    float* ls = mu + (size_t)N * 32;

    const int nblocks = (N + 255) / 256;   // 391
    const int s1blocks = (E + CHUNK - 1) / CHUNK;   // 391

    // ---- 2-level counting sort into padded CSR ----
    hipMemsetAsync(cbin, 0, 1024 * sizeof(int), stream);
    prefill_kernel<<<(PADMAX + 255) / 256, 256, 0, stream>>>(ssrc, N, PADMAX);
    chist_kernel<<<256, 256, 0, stream>>>(dstp, cbin, E, NCB);
    cscan_kernel<<<1, 256, 0, stream>>>(cbin, cboff, ccur16, NCB);
    scat1_kernel<<<s1blocks, 256, 0, stream>>>(src, dstp, ccur16, pairs, E);
    degbuild_kernel<<<NCB, 256, 0, stream>>>(pairs, cboff, dis, dpad, N);
    scan_block_sums<<<nblocks, 256, 0, stream>>>(dpad, bsum, N);
    scan_partials<<<1, 512, 0, stream>>>(bsum, nblocks, rp + N);
    scan_final<<<nblocks, 256, 0, stream>>>(dpad, bsum, rp, N);
    scat2_kernel<<<NCB, 256, 0, stream>>>(pairs, cboff, rp, ssrc, N);

    // ---- Hs1 = (x@W1)*dis (bf16); zero dummy row N in both buffers ----
    gemm1_kernel<<<N / 16, 256, 0, stream>>>(x, W1, dis, bufH0, N);
    hipMemsetAsync(bufH0 + (size_t)N * 64, 0, 128, stream);
    hipMemsetAsync(bufH1 + (size_t)N * 64, 0, 128, stream);

    const int aggblocks = 2048;  // 8192 waves, grid-stride

    aggA_kernel<<<aggblocks, 256, 0, stream>>>(bufH0, rp, ssrc, dis, b1, W2, bufH1, N);
    aggB_kernel<<<aggblocks, 256, 0, stream>>>(bufH1, rp, ssrc, dis, b2, bufH0, N);
    aggC_kernel<<<aggblocks, 256, 0, stream>>>(bufH0, rp, ssrc, dis, Wmu, bmu,
                                               Wls, bls, mu, ls, N);
}

// Round 8
// 305.265 us; speedup vs baseline: 2.1258x; 1.0069x over previous
//
#include <hip/hip_runtime.h>

#define LEAKY_SLOPE 0.01f
#define CBSH 7
#define CBSZ 128          // nodes per coarse bucket
#define CHUNK 4096        // edges per scat1 block

__device__ __forceinline__ unsigned short f2bf(float f) {
    unsigned int u = __builtin_bit_cast(unsigned int, f);
    u = (u + 0x7FFFu + ((u >> 16) & 1u)) >> 16;   // round-to-nearest-even
    return (unsigned short)u;
}
__device__ __forceinline__ float bf2f(unsigned short h) {
    return __builtin_bit_cast(float, ((unsigned int)h) << 16);
}
__device__ __forceinline__ float ulof(unsigned u) {
    return __builtin_bit_cast(float, u << 16);
}
__device__ __forceinline__ float uhif(unsigned u) {
    return __builtin_bit_cast(float, u & 0xFFFF0000u);
}
__device__ __forceinline__ float bcastf(int hb, int k) {
    return __builtin_bit_cast(float, __builtin_amdgcn_readlane(hb, k));
}

// ---------------------------------------------------------------------------
// coarse histogram by dst>>7 (LDS-privatized)
// ---------------------------------------------------------------------------
__global__ __launch_bounds__(256) void chist_kernel(const int* __restrict__ dst,
                                                    int* __restrict__ cbin, int E, int ncb) {
    __shared__ int bins[1024];
    for (int i = threadIdx.x; i < 1024; i += 256) bins[i] = 0;
    __syncthreads();
    int stride = gridDim.x * blockDim.x;
    for (int e = blockIdx.x * blockDim.x + threadIdx.x; e < E; e += stride)
        atomicAdd(&bins[dst[e] >> CBSH], 1);
    __syncthreads();
    for (int i = threadIdx.x; i < ncb; i += 256) {
        int v = bins[i];
        if (v) atomicAdd(&cbin[i], v);
    }
}

// single-block scan of coarse bins -> offsets + 64B-strided cursor init
__global__ __launch_bounds__(256) void cscan_kernel(const int* __restrict__ cbin,
                                                    int* __restrict__ cboff,
                                                    int* __restrict__ ccur16, int ncb) {
    __shared__ int s[256];
    __shared__ int carry;
    int t = threadIdx.x;
    if (t == 0) carry = 0;
    __syncthreads();
    for (int base = 0; base < ncb; base += 256) {
        int v = (base + t < ncb) ? cbin[base + t] : 0;
        s[t] = v;
        __syncthreads();
        for (int off = 1; off < 256; off <<= 1) {
            int u = (t >= off) ? s[t - off] : 0;
            __syncthreads();
            s[t] += u;
            __syncthreads();
        }
        int excl = carry + s[t] - v;
        if (base + t < ncb) { cboff[base + t] = excl; ccur16[(size_t)(base + t) * 16] = excl; }
        __syncthreads();
        if (t == 0) carry += s[255];
        __syncthreads();
    }
    if (t == 0) cboff[ncb] = carry;
}

// ---------------------------------------------------------------------------
// blocked level-1 scatter: per-block LDS histogram -> one global atomic per
// (block,bucket) chunk reservation -> LDS-cursor scatter.
// ---------------------------------------------------------------------------
__global__ __launch_bounds__(256) void scat1_kernel(const int* __restrict__ src,
                                                    const int* __restrict__ dst,
                                                    int* __restrict__ ccur16,
                                                    unsigned* __restrict__ pairs, int E) {
    __shared__ int bins[1024];
    __shared__ int base[1024];
    int t = threadIdx.x;
    for (int i = t; i < 1024; i += 256) bins[i] = 0;
    __syncthreads();
    int e0 = blockIdx.x * CHUNK;
    int m = min(CHUNK, E - e0);
    for (int i = t; i < m; i += 256)
        atomicAdd(&bins[dst[e0 + i] >> CBSH], 1);
    __syncthreads();
    for (int i = t; i < 1024; i += 256) {
        int c = bins[i];
        base[i] = c ? atomicAdd(&ccur16[(size_t)i * 16], c) : 0;
        bins[i] = 0;   // reuse as local cursor
    }
    __syncthreads();
    for (int i = t; i < m; i += 256) {
        int d = dst[e0 + i];
        int b = d >> CBSH;
        int off = atomicAdd(&bins[b], 1);
        pairs[base[b] + off] = (unsigned)src[e0 + i] | ((unsigned)(d & (CBSZ - 1)) << 17);
    }
}

// per-bucket degree (LDS histogram) -> dis + padded degree (multiple of 16)
__global__ __launch_bounds__(256) void degbuild_kernel(const unsigned* __restrict__ pairs,
                                                       const int* __restrict__ cboff,
                                                       float* __restrict__ dis,
                                                       int* __restrict__ dpad, int n) {
    __shared__ int cnt[CBSZ];
    int t = threadIdx.x;
    int b = blockIdx.x;
    if (t < CBSZ) cnt[t] = 0;
    __syncthreads();
    int e1 = cboff[b + 1];
    for (int e = cboff[b] + t; e < e1; e += 256)
        atomicAdd(&cnt[pairs[e] >> 17], 1);
    __syncthreads();
    if (t < CBSZ) {
        int node = b * CBSZ + t;
        if (node < n) {
            int d = cnt[t];
            dis[node] = rsqrtf((float)d + 1.0f);
            dpad[node] = (d + 15) & ~15;
        }
    }
}

// ---------------------------------------------------------------------------
// scan chain over padded degrees -> rp (padded CSR offsets)
// ---------------------------------------------------------------------------
__global__ void scan_block_sums(const int* __restrict__ deg, int* __restrict__ bsum, int n) {
    __shared__ int sdata[256];
    int i = blockIdx.x * 256 + threadIdx.x;
    int t = threadIdx.x;
    sdata[t] = (i < n) ? deg[i] : 0;
    __syncthreads();
    for (int s = 128; s > 0; s >>= 1) {
        if (t < s) sdata[t] += sdata[t + s];
        __syncthreads();
    }
    if (t == 0) bsum[blockIdx.x] = sdata[0];
}

__global__ void scan_partials(int* __restrict__ bsum, int nb, int* __restrict__ rp_end) {
    __shared__ int s[512];
    int t = threadIdx.x;
    int orig = (t < nb) ? bsum[t] : 0;
    s[t] = orig;
    __syncthreads();
    for (int off = 1; off < 512; off <<= 1) {
        int v = (t >= off) ? s[t - off] : 0;
        __syncthreads();
        s[t] += v;
        __syncthreads();
    }
    if (t < nb) bsum[t] = s[t] - orig;   // exclusive
    if (t == 0) rp_end[0] = s[511];      // total padded edges
}

__global__ void scan_final(const int* __restrict__ deg, const int* __restrict__ bsum,
                           int* __restrict__ rp, int n) {
    __shared__ int s[256];
    int i = blockIdx.x * 256 + threadIdx.x;
    int t = threadIdx.x;
    int orig = (i < n) ? deg[i] : 0;
    s[t] = orig;
    __syncthreads();
    for (int off = 1; off < 256; off <<= 1) {
        int v = (t >= off) ? s[t - off] : 0;
        __syncthreads();
        s[t] += v;
        __syncthreads();
    }
    if (i < n) rp[i] = s[t] - orig + bsum[blockIdx.x];
}

// level-2 scatter + pad fill: place edges at exact padded CSR positions via
// LDS cursors, then fill each node's pad slots (<=15) with dummy index n.
__global__ __launch_bounds__(256) void scat2_kernel(const unsigned* __restrict__ pairs,
                                                    const int* __restrict__ cboff,
                                                    const int* __restrict__ rp,
                                                    int* __restrict__ ssrc, int n) {
    __shared__ int lrp[CBSZ];
    __shared__ int lcnt[CBSZ];
    int t = threadIdx.x;
    int b = blockIdx.x;
    if (t < CBSZ) {
        int node = b * CBSZ + t;
        lrp[t] = (node < n) ? rp[node] : 0;
        lcnt[t] = 0;
    }
    __syncthreads();
    int e1 = cboff[b + 1];
    for (int e = cboff[b] + t; e < e1; e += 256) {
        unsigned p = pairs[e];
        int dl = p >> 17;
        int off = atomicAdd(&lcnt[dl], 1);
        ssrc[lrp[dl] + off] = (int)(p & 0x1FFFFu);
    }
    __syncthreads();
    if (t < CBSZ) {
        int node = b * CBSZ + t;
        if (node < n) {
            int c0 = lcnt[t];
            int cpad = (c0 + 15) & ~15;
            int base = lrp[t];
            for (int i = c0; i < cpad; ++i) ssrc[base + i] = n;
        }
    }
}

// ---------------------------------------------------------------------------
// gemm1: Hs1 = (X[N,128] @ W1[128,64]) * dis -> bf16
// ---------------------------------------------------------------------------
__global__ __launch_bounds__(256) void gemm1_kernel(const float* __restrict__ X,
                                                    const float* __restrict__ W,
                                                    const float* __restrict__ dis,
                                                    unsigned short* __restrict__ Hh, int N) {
    __shared__ float Xs[16 * 128];
    int tid = threadIdx.x;
    int row0 = blockIdx.x * 16;
    for (int i = tid * 4; i < 16 * 128; i += 256 * 4)
        *(float4*)&Xs[i] = *(const float4*)&X[(size_t)row0 * 128 + i];
    __syncthreads();

    int c = tid & 63;
    int g = tid >> 6;
    float acc[4] = {0.f, 0.f, 0.f, 0.f};
    for (int kk = 0; kk < 128; kk += 16) {
        float w[16];
#pragma unroll
        for (int k = 0; k < 16; ++k) w[k] = W[(kk + k) * 64 + c];
#pragma unroll
        for (int r = 0; r < 4; ++r) {
            int row = g + r * 4;
#pragma unroll
            for (int k4 = 0; k4 < 16; k4 += 4) {
                float4 x4 = *(float4*)&Xs[row * 128 + kk + k4];
                acc[r] += x4.x * w[k4] + x4.y * w[k4 + 1] + x4.z * w[k4 + 2] + x4.w * w[k4 + 3];
            }
        }
    }
#pragma unroll
    for (int r = 0; r < 4; ++r) {
        int row = row0 + g + r * 4;
        Hh[(size_t)row * 64 + c] = f2bf(acc[r] * dis[row]);
    }
}

// ---------------------------------------------------------------------------
// Wide gather: 4 lane-groups x 16 lanes; group g consumes the contiguous edge
// quad sp[i+4g..i+4g+3] via ONE int4 load (rp padded to x16 -> 16B aligned);
// each lane loads ushort4 (4 channels, 8B). 5 VMEM issues per 16 edges.
// ---------------------------------------------------------------------------
#define GATHER_WIDE(Hh, wid, lane, accv)                                       \
    float accv;                                                                \
    {                                                                          \
        int gg = (lane) >> 4, cc = (lane) & 15;                                \
        float ac0 = 0.f, ac1 = 0.f, ac2 = 0.f, ac3 = 0.f;                      \
        int e0 = rp[wid], e1 = rp[(wid) + 1];                                  \
        const int* sp = ssrc + e0;                                             \
        int cnt = e1 - e0;                                                     \
        for (int i = 0; i < cnt; i += 16) {                                    \
            int4 s4 = *(const int4*)&sp[i + gg * 4];                           \
            uint2 q0 = *(const uint2*)&Hh[(size_t)s4.x * 64 + cc * 4];         \
            uint2 q1 = *(const uint2*)&Hh[(size_t)s4.y * 64 + cc * 4];         \
            uint2 q2 = *(const uint2*)&Hh[(size_t)s4.z * 64 + cc * 4];         \
            uint2 q3 = *(const uint2*)&Hh[(size_t)s4.w * 64 + cc * 4];         \
            ac0 += (ulof(q0.x) + ulof(q1.x)) + (ulof(q2.x) + ulof(q3.x));      \
            ac1 += (uhif(q0.x) + uhif(q1.x)) + (uhif(q2.x) + uhif(q3.x));      \
            ac2 += (ulof(q0.y) + ulof(q1.y)) + (ulof(q2.y) + ulof(q3.y));      \
            ac3 += (uhif(q0.y) + uhif(q1.y)) + (uhif(q2.y) + uhif(q3.y));      \
        }                                                                      \
        ac0 += __shfl_xor(ac0, 16); ac0 += __shfl_xor(ac0, 32);                \
        ac1 += __shfl_xor(ac1, 16); ac1 += __shfl_xor(ac1, 32);                \
        ac2 += __shfl_xor(ac2, 16); ac2 += __shfl_xor(ac2, 32);                \
        ac3 += __shfl_xor(ac3, 16); ac3 += __shfl_xor(ac3, 32);                \
        int srcl = (lane) >> 2;                                                \
        float v0 = __shfl(ac0, srcl);                                          \
        float v1 = __shfl(ac1, srcl);                                          \
        float v2 = __shfl(ac2, srcl);                                          \
        float v3 = __shfl(ac3, srcl);                                          \
        int jj = (lane) & 3;                                                   \
        accv = jj == 0 ? v0 : (jj == 1 ? v1 : (jj == 2 ? v2 : v3));            \
        accv += bf2f(Hh[(size_t)(wid) * 64 + (lane)]);                         \
    }

// LDS matvec epilogue: Ws[k*64+lane] layout, 2 lanes/bank (free), 4-way
// split accumulator chain. Returns o (no bias).
#define LDS_MATVEC(hb, lane, Ws, o)                                            \
    float o;                                                                   \
    {                                                                          \
        float o0 = 0.f, o1 = 0.f, o2 = 0.f, o3 = 0.f;                          \
        _Pragma("unroll")                                                      \
        for (int k = 0; k < 64; k += 4) {                                      \
            o0 = fmaf(bcastf(hb, k),     Ws[(k)*64 + (lane)],     o0);         \
            o1 = fmaf(bcastf(hb, k + 1), Ws[(k+1)*64 + (lane)], o1);           \
            o2 = fmaf(bcastf(hb, k + 2), Ws[(k+2)*64 + (lane)], o2);           \
            o3 = fmaf(bcastf(hb, k + 3), Ws[(k+3)*64 + (lane)], o3);           \
        }                                                                      \
        o = (o0 + o1) + (o2 + o3);                                             \
    }

// ---------------------------------------------------------------------------
// aggA: h1 = leaky(dis*agg(Hs1) + b1); Hs2 = (h1 @ W2)*dis -> bf16
// W2 staged in LDS (16KB).
// ---------------------------------------------------------------------------
__global__ __launch_bounds__(256) void aggA_kernel(
    const unsigned short* __restrict__ Hh, const int* __restrict__ rp,
    const int* __restrict__ ssrc, const float* __restrict__ dis,
    const float* __restrict__ b1, const float* __restrict__ W2,
    unsigned short* __restrict__ Oh, int n) {
    __shared__ float Ws[64 * 64];
    for (int i = threadIdx.x * 4; i < 4096; i += 256 * 4)
        *(float4*)&Ws[i] = *(const float4*)&W2[i];
    __syncthreads();

    int lane = threadIdx.x & 63;
    float bias = b1[lane];

    int wid = (int)((blockIdx.x * blockDim.x + threadIdx.x) >> 6);
    int nwaves = (int)((gridDim.x * blockDim.x) >> 6);
    for (; wid < n; wid += nwaves) {
        GATHER_WIDE(Hh, wid, lane, accv)
        float d = dis[wid];
        float h = fmaf(accv, d, bias);
        h = h > 0.f ? h : LEAKY_SLOPE * h;
        int hb = __builtin_bit_cast(int, h);
        LDS_MATVEC(hb, lane, Ws, o)
        Oh[(size_t)wid * 64 + lane] = f2bf(o * d);
    }
}

// ---------------------------------------------------------------------------
// aggB: h2 = leaky(dis*agg(Hs2) + b2); h2s = h2*dis -> bf16
// ---------------------------------------------------------------------------
__global__ __launch_bounds__(256) void aggB_kernel(
    const unsigned short* __restrict__ Hh, const int* __restrict__ rp,
    const int* __restrict__ ssrc, const float* __restrict__ dis,
    const float* __restrict__ b2, unsigned short* __restrict__ Oh, int n) {
    int lane = threadIdx.x & 63;
    float bias = b2[lane];
    int wid = (int)((blockIdx.x * blockDim.x + threadIdx.x) >> 6);
    int nwaves = (int)((gridDim.x * blockDim.x) >> 6);
    for (; wid < n; wid += nwaves) {
        GATHER_WIDE(Hh, wid, lane, accv)
        float d = dis[wid];
        float h = fmaf(accv, d, bias);
        h = h > 0.f ? h : LEAKY_SLOPE * h;
        Oh[(size_t)wid * 64 + lane] = f2bf(h * d);
    }
}

// ---------------------------------------------------------------------------
// aggC: g = dis*agg(h2s); mu = g@Wmu + bmu; ls = g@Wls + bls -> d_out
// Wmu|Wls interleaved in one LDS array: Ws[k*64+c] = (c<32 ? Wmu : Wls).
// ---------------------------------------------------------------------------
__global__ __launch_bounds__(256) void aggC_kernel(
    const unsigned short* __restrict__ Hh, const int* __restrict__ rp,
    const int* __restrict__ ssrc, const float* __restrict__ dis,
    const float* __restrict__ Wmu, const float* __restrict__ bmu,
    const float* __restrict__ Wls, const float* __restrict__ bls,
    float* __restrict__ mu, float* __restrict__ ls, int n) {
    __shared__ float Ws[64 * 64];
    for (int i = threadIdx.x; i < 4096; i += 256) {
        int k = i >> 6, c = i & 63;
        Ws[i] = (c < 32) ? Wmu[k * 32 + c] : Wls[k * 32 + (c - 32)];
    }
    __syncthreads();

    int lane = threadIdx.x & 63;
    int half = lane >> 5;
    int c = lane & 31;
    float bias = half ? bls[c] : bmu[c];
    float* outp = half ? ls : mu;

    int wid = (int)((blockIdx.x * blockDim.x + threadIdx.x) >> 6);
    int nwaves = (int)((gridDim.x * blockDim.x) >> 6);
    for (; wid < n; wid += nwaves) {
        GATHER_WIDE(Hh, wid, lane, accv)
        float gval = accv * dis[wid];
        int gb = __builtin_bit_cast(int, gval);
        LDS_MATVEC(gb, lane, Ws, o)
        outp[(size_t)wid * 32 + c] = o + bias;
    }
}

// ---------------------------------------------------------------------------
extern "C" void kernel_launch(void* const* d_in, const int* in_sizes, int n_in,
                              void* d_out, int out_size, void* d_ws, size_t ws_size,
                              hipStream_t stream) {
    const float* x   = (const float*)d_in[0];
    const int*   ei  = (const int*)d_in[1];
    const float* W1  = (const float*)d_in[2];
    const float* b1  = (const float*)d_in[3];
    const float* W2  = (const float*)d_in[4];
    const float* b2  = (const float*)d_in[5];
    const float* Wmu = (const float*)d_in[6];
    const float* bmu = (const float*)d_in[7];
    const float* Wls = (const float*)d_in[8];
    const float* bls = (const float*)d_in[9];

    const int N = in_sizes[0] / 128;   // 100000
    const int E = in_sizes[1] / 2;     // 1600000
    const int NCB = (N + CBSZ - 1) / CBSZ;   // 782 coarse buckets
    const int PADMAX = E + 15 * ((N + 15) / 16) * 16 + 64;  // padded edges upper bound
    const int* src  = ei;
    const int* dstp = ei + E;

    auto align64 = [](size_t v) { return (v + 63) & ~(size_t)63; };
    char* ws = (char*)d_ws;
    int*   dpad   = (int*)ws;   ws += align64((size_t)N * 4);
    float* dis    = (float*)ws; ws += align64((size_t)N * 4);
    int*   cbin   = (int*)ws;   ws += align64(1024 * 4);
    int*   cboff  = (int*)ws;   ws += align64(1025 * 4);
    int*   ccur16 = (int*)ws;   ws += align64((size_t)1024 * 16 * 4);
    int*   bsum   = (int*)ws;   ws += 4096;
    int*   rp     = (int*)ws;   ws += align64((size_t)(N + 1) * 4);
    unsigned* pairs = (unsigned*)ws; ws += align64((size_t)E * 4);
    int*   ssrc   = (int*)ws;   ws += align64((size_t)PADMAX * 4);
    unsigned short* bufH0 = (unsigned short*)ws; ws += align64(((size_t)N + 1) * 64 * 2);
    unsigned short* bufH1 = (unsigned short*)ws; ws += align64(((size_t)N + 1) * 64 * 2);

    float* mu = (float*)d_out;
    float* ls = mu + (size_t)N * 32;

    const int nblocks = (N + 255) / 256;   // 391
    const int s1blocks = (E + CHUNK - 1) / CHUNK;   // 391

    // ---- 2-level counting sort into padded CSR ----
    hipMemsetAsync(cbin, 0, 1024 * sizeof(int), stream);
    chist_kernel<<<256, 256, 0, stream>>>(dstp, cbin, E, NCB);
    cscan_kernel<<<1, 256, 0, stream>>>(cbin, cboff, ccur16, NCB);
    scat1_kernel<<<s1blocks, 256, 0, stream>>>(src, dstp, ccur16, pairs, E);
    degbuild_kernel<<<NCB, 256, 0, stream>>>(pairs, cboff, dis, dpad, N);
    scan_block_sums<<<nblocks, 256, 0, stream>>>(dpad, bsum, N);
    scan_partials<<<1, 512, 0, stream>>>(bsum, nblocks, rp + N);
    scan_final<<<nblocks, 256, 0, stream>>>(dpad, bsum, rp, N);
    scat2_kernel<<<NCB, 256, 0, stream>>>(pairs, cboff, rp, ssrc, N);

    // ---- Hs1 = (x@W1)*dis (bf16); zero dummy row N in both buffers ----
    gemm1_kernel<<<N / 16, 256, 0, stream>>>(x, W1, dis, bufH0, N);
    hipMemsetAsync(bufH0 + (size_t)N * 64, 0, 128, stream);
    hipMemsetAsync(bufH1 + (size_t)N * 64, 0, 128, stream);

    const int aggblocks = 2048;  // 8192 waves, grid-stride

    aggA_kernel<<<aggblocks, 256, 0, stream>>>(bufH0, rp, ssrc, dis, b1, W2, bufH1, N);
    aggB_kernel<<<aggblocks, 256, 0, stream>>>(bufH1, rp, ssrc, dis, b2, bufH0, N);
    aggC_kernel<<<aggblocks, 256, 0, stream>>>(bufH0, rp, ssrc, dis, Wmu, bmu,
                                               Wls, bls, mu, ls, N);
}